// Round 14
// baseline (174.821 us; speedup 1.0000x reference)
//
#include <hip/hip_runtime.h>
#include <stdint.h>

#define BATCH 8
#define NCLS 80
#define MAXDET 100
#define CAP 512
#define NBINS 10240          // keys 0..10036 (score 1.0) fit without clamping
#define HT_THREADS 1024
#define HT_CHUNKB 10         // 1024 threads * 10 bins = 10240
#define BASEKEY (0x3D4CCCCDu >> 12)   // float bits of 0.05f >> 12

// ---------------- Kernel 1: scores, 2 lanes per row, float4 loads, bit-exact ----
__global__ __launch_bounds__(256)
void scores_kernel(const float* __restrict__ cls,
                   float* __restrict__ scores, int BN) {
  int gid = blockIdx.x * 256 + threadIdx.x;
  int row = gid >> 1;
  int l = gid & 1;
  if (row >= BN) return;
  const float4* p4 = (const float4*)(cls + (size_t)row * NCLS);

  float4 v[10];
#pragma unroll
  for (int i = 0; i < 10; i++) v[i] = p4[l + 2 * i];

  float m = fmaxf(fmaxf(v[0].x, v[0].y), fmaxf(v[0].z, v[0].w));
#pragma unroll
  for (int i = 1; i < 10; i++)
    m = fmaxf(m, fmaxf(fmaxf(v[i].x, v[i].y), fmaxf(v[i].z, v[i].w)));
  m = fmaxf(m, __shfl_xor(m, 1));

  float a0 = 0.f, a1 = 0.f, a2 = 0.f, a3 = 0.f;
#pragma unroll
  for (int i = 0; i < 10; i++) {
    a0 += expf(v[i].x - m);
    a1 += expf(v[i].y - m);
    a2 += expf(v[i].z - m);
    a3 += expf(v[i].w - m);
  }
  float s_half = (a0 + a1) + (a2 + a3);      // (r8[4l]+r8[4l+1])+(r8[4l+2]+r8[4l+3])
  float s = s_half + __shfl_xor(s_half, 1);  // half0 + half1
  if (l == 0) scores[row] = 1.0f / s;
}

// ---------------- Kernel 2: per-batch LDS histogram + threshold ----------------
__global__ __launch_bounds__(HT_THREADS)
void histthresh_kernel(const float* __restrict__ scores,
                       uint32_t* __restrict__ Tb, uint32_t* __restrict__ ctr, int N) {
  __shared__ uint32_t lh[NBINS];
  __shared__ uint32_t chs[HT_THREADS];
  const int b = blockIdx.x;
  const int tid = threadIdx.x;

#pragma unroll
  for (int j = 0; j < HT_CHUNKB; j++) lh[tid + j * HT_THREADS] = 0;
  __syncthreads();

  const float* sc = scores + (size_t)b * N;
  for (int i = tid; i < N; i += HT_THREADS) {
    float s = sc[i];
    if (s >= 0.05f) {
      uint32_t key = (__float_as_uint(s) >> 12) - BASEKEY;
      atomicAdd(&lh[key], 1u);
    }
  }
  __syncthreads();

  uint32_t csum = 0;
#pragma unroll
  for (int j = 0; j < HT_CHUNKB; j++) csum += lh[tid * HT_CHUNKB + j];
  chs[tid] = csum;
  __syncthreads();
  for (int off = 1; off < HT_THREADS; off <<= 1) {
    uint32_t v = chs[tid];
    uint32_t add = (tid + off < HT_THREADS) ? chs[tid + off] : 0u;
    __syncthreads();
    chs[tid] = v + add;
    __syncthreads();
  }
  uint32_t St = chs[tid];
  uint32_t Sprev = (tid > 0) ? chs[tid - 1] : 0xFFFFFFFFu;
  if (St <= CAP && (tid == 0 || Sprev > CAP)) {
    int T = 0;
    if (tid != 0) {
      uint32_t cum = St;
      int lo = (tid - 1) * HT_CHUNKB;
      T = lo;
      for (int bb = tid * HT_CHUNKB - 1; bb >= lo; bb--) {
        uint32_t nb = cum + lh[bb];
        if (nb > CAP) { T = bb + 1; break; }
        cum = nb;
        if (bb == lo) T = lo;
      }
    }
    Tb[b] = (uint32_t)T;
  }
  if (tid == 0) ctr[b] = 0;
}

// ---------------- Kernel 3: hierarchical compact (1 atomic per block) ----------------
__global__ __launch_bounds__(1024)
void compact_kernel(const float* __restrict__ scores,
                    const uint32_t* __restrict__ Tb,
                    uint32_t* __restrict__ ctr,
                    uint32_t* __restrict__ csb, uint32_t* __restrict__ cidx,
                    int N) {
  __shared__ uint32_t wbase[16];
  __shared__ uint32_t blkbase;
  const int b = blockIdx.y;
  const int i = blockIdx.x * 1024 + threadIdx.x;
  const int lane = threadIdx.x & 63, wid = threadIdx.x >> 6;

  bool q = false;
  float s = 0.f;
  if (i < N) {
    s = scores[(size_t)b * N + i];
    if (s >= 0.05f) {
      uint32_t key = (__float_as_uint(s) >> 12) - BASEKEY;
      q = key >= Tb[b];
    }
  }
  unsigned long long mask = __ballot(q);
  uint32_t wcnt = (uint32_t)__popcll(mask);
  uint32_t lpre = (uint32_t)__popcll(mask & ((1ULL << lane) - 1ULL));
  if (lane == 0) wbase[wid] = wcnt;
  __syncthreads();
  if (threadIdx.x == 0) {
    uint32_t tot = 0;
#pragma unroll
    for (int w = 0; w < 16; w++) { uint32_t c = wbase[w]; wbase[w] = tot; tot += c; }
    blkbase = tot ? atomicAdd(&ctr[b], tot) : 0u;
  }
  __syncthreads();
  if (q) {
    uint32_t slot = blkbase + wbase[wid] + lpre;
    if (slot < CAP) {
      csb[b * CAP + slot] = __float_as_uint(s);
      cidx[b * CAP + slot] = (uint32_t)i;
    }
  }
}

// ---------------- Kernel 4: sort + all-resident single-wave NMS + fused output ----
// All 512 sorted candidates live in wave0 registers (8 slots/lane, slot =
// j*64+lane so sorted order == (j, lane) lexicographic). Per accept: <=8
// ballots find the first alive slot, one uniform ds_read_b128 broadcasts the
// pick, each lane tests its own <=8 register-resident candidates. Exact
// shortcut: non-proper boxes (c<=a || d<=b) have inter==0 -> never suppress
// and can't be suppressed -> skipped via supp mask / uniform branch.
__global__ __launch_bounds__(256, 1)
void nmsout_kernel(const float* __restrict__ box, const float* __restrict__ cls,
                   const uint32_t* __restrict__ csb, const uint32_t* __restrict__ cidx,
                   const uint32_t* __restrict__ ctr,
                   float* __restrict__ out, int N) {
  __shared__ unsigned long long sk[CAP];
  __shared__ float sbox[CAP][4];
  __shared__ uint32_t sidx[CAP];
  __shared__ float4 accb[MAXDET];
  __shared__ uint32_t pick_i[MAXDET];
  __shared__ int nacc_sh;

  const int b = blockIdx.x;
  const int tid = threadIdx.x;
  uint32_t nc = ctr[b]; if (nc > CAP) nc = CAP;

#pragma unroll
  for (int q = 0; q < CAP / 256; q++) {
    int s = tid + q * 256;
    unsigned long long k = 0ULL;
    if (s < (int)nc)
      k = ((unsigned long long)csb[b * CAP + s] << 32) |
          (unsigned long long)(cidx[b * CAP + s] ^ 0xFFFFFFFFu);
    sk[s] = k;
  }
  __syncthreads();

  // bitonic sort, descending
  for (int k = 2; k <= CAP; k <<= 1) {
    for (int j = k >> 1; j > 0; j >>= 1) {
#pragma unroll
      for (int q = 0; q < CAP / 256; q++) {
        int i = tid + q * 256;
        int ixj = i ^ j;
        if (ixj > i) {
          unsigned long long a = sk[i], c = sk[ixj];
          if (((i & k) == 0) ? (a < c) : (a > c)) { sk[i] = c; sk[ixj] = a; }
        }
      }
      __syncthreads();
    }
  }

  // gather boxes of sorted candidates into LDS (corner-interp xywh form)
#pragma unroll
  for (int q = 0; q < CAP / 256; q++) {
    int s = tid + q * 256;
    unsigned long long k = sk[s];
    uint32_t idx = (uint32_t)k ^ 0xFFFFFFFFu;
    sidx[s] = idx;
    if (k != 0ULL) {
      const float4 f = *(const float4*)(box + ((size_t)b * N + idx) * 4);
      sbox[s][0] = f.x; sbox[s][1] = f.y; sbox[s][2] = f.z - f.x; sbox[s][3] = f.w - f.y;
    } else {
      sbox[s][0] = 0.f; sbox[s][1] = 0.f; sbox[s][2] = 0.f; sbox[s][3] = 0.f;
    }
  }
  __syncthreads();

  if (tid < 64) {   // wave0-only walk, no barriers inside
    const int lane = tid;
    const int SPL = CAP / 64;            // 8 slots per lane, strided
    float bx[SPL][4];
    float ab[SPL];
    uint32_t alive = 0, supp = 0;
#pragma unroll
    for (int j = 0; j < SPL; j++) {
      int s = j * 64 + lane;
      bx[j][0] = sbox[s][0]; bx[j][1] = sbox[s][1];
      bx[j][2] = sbox[s][2]; bx[j][3] = sbox[s][3];
      ab[j] = (bx[j][2] - bx[j][0]) * (bx[j][3] - bx[j][1]);
      if (s < (int)nc) alive |= (1u << j);
      if (bx[j][2] > bx[j][0] && bx[j][3] > bx[j][1]) supp |= (1u << j);
    }

    int nacc = 0;
    while (nacc < MAXDET) {
      // find first alive slot in sorted order (j-major, then lane)
      int jsel = -1, Lsel = 0;
#pragma unroll
      for (int j = 0; j < SPL; j++) {
        if (jsel < 0) {
          unsigned long long mm = __ballot((alive >> j) & 1u);
          if (mm != 0ULL) { jsel = j; Lsel = (int)(__ffsll(mm) - 1); }
        }
      }
      if (jsel < 0) break;
      const int p = jsel * 64 + Lsel;
      // broadcast pick via uniform LDS read
      float r0 = sbox[p][0], r1 = sbox[p][1], r2 = sbox[p][2], r3 = sbox[p][3];
      if (lane == 0) {
        pick_i[nacc] = sidx[p];              // fire-and-forget (read after barrier)
        accb[nacc] = make_float4(r0, r1, r2, r3);
      }
      if (lane == Lsel) alive &= ~(1u << jsel);

      if (r2 > r0 && r3 > r1) {              // proper pick box: can suppress (exact)
        const float area_r = (r2 - r0) * (r3 - r1);
        const uint32_t test = alive & supp;
#pragma unroll
        for (int j = 0; j < SPL; j++) {
          if ((test >> j) & 1u) {
            float ih = fmaxf(0.f, fminf(r2, bx[j][2]) - fmaxf(r0, bx[j][0]));
            float iw = fmaxf(0.f, fminf(r3, bx[j][3]) - fmaxf(r1, bx[j][1]));
            float inter = ih * iw;
            float uni = area_r + ab[j] - inter;
            bool okk = (area_r > 0.f) && (ab[j] > 0.f) && (uni > 0.f);
            float iou = okk ? (inter / uni) : 0.f;
            if (iou > 0.5f) alive &= ~(1u << j);
          }
        }
      }
      nacc++;
    }
    if (lane == 0) nacc_sh = nacc;
  }
  __syncthreads();

  // -------- fused output phase: threads 0..MAXDET-1 each own one pick slot ----
  const int nacc = nacc_sh;
  if (tid >= MAXDET) return;
  const int r = b * MAXDET + tid;
  float* boxes_out  = out;
  float* clsidx_out = out + BATCH * MAXDET * 4;
  float* cls_out    = out + BATCH * MAXDET * 4 + BATCH * MAXDET;

  if (tid >= nacc) {
    boxes_out[r * 4 + 0] = 0.f; boxes_out[r * 4 + 1] = 0.f;
    boxes_out[r * 4 + 2] = 0.f; boxes_out[r * 4 + 3] = 0.f;
    clsidx_out[r] = 0.f;
    for (int j = 0; j < NCLS; j++) cls_out[r * NCLS + j] = 0.f;
    return;
  }
  float4 bb = accb[tid];
  boxes_out[r * 4 + 0] = bb.x;
  boxes_out[r * 4 + 1] = bb.y;
  boxes_out[r * 4 + 2] = bb.z;
  boxes_out[r * 4 + 3] = bb.w;

  uint32_t idx = pick_i[tid];
  const float4* p = (const float4*)(cls + ((size_t)b * N + idx) * NCLS);
  float x[NCLS];
#pragma unroll
  for (int i = 0; i < NCLS / 4; i++) {
    float4 v = p[i];
    x[4 * i] = v.x; x[4 * i + 1] = v.y; x[4 * i + 2] = v.z; x[4 * i + 3] = v.w;
  }
  float m = x[0];
#pragma unroll
  for (int i = 1; i < NCLS; i++) m = fmaxf(m, x[i]);
  float r8[8];
#pragma unroll
  for (int j = 0; j < 8; j++) r8[j] = 0.0f;
#pragma unroll
  for (int i = 0; i < NCLS / 8; i++)
#pragma unroll
    for (int j = 0; j < 8; j++) r8[j] += expf(x[i * 8 + j] - m);
  float s = ((r8[0] + r8[1]) + (r8[2] + r8[3])) + ((r8[4] + r8[5]) + (r8[6] + r8[7]));

  float best = -1.f; int bi = 0;
  for (int j = 0; j < NCLS; j++) {
    float pj = expf(x[j] - m) / s;
    cls_out[r * NCLS + j] = pj;
    if (pj > best) { best = pj; bi = j; }
  }
  clsidx_out[r] = (float)bi;
}

extern "C" void kernel_launch(void* const* d_in, const int* in_sizes, int n_in,
                              void* d_out, int out_size, void* d_ws, size_t ws_size,
                              hipStream_t stream) {
  (void)n_in; (void)out_size; (void)ws_size;
  const float* box = (const float*)d_in[0];
  const float* cls = (const float*)d_in[1];
  const int N = in_sizes[0] / (BATCH * 4);
  const int BN = BATCH * N;

  float*    ws_scores = (float*)d_ws;                          // BN floats
  uint32_t* ctr   = (uint32_t*)(ws_scores + (size_t)BN);       // BATCH
  uint32_t* Tb    = ctr + BATCH;                               // BATCH
  uint32_t* csb   = Tb + BATCH;                                // BATCH*CAP
  uint32_t* cidx  = csb + BATCH * CAP;                         // BATCH*CAP

  {
    long long tot = (long long)BN * 2;
    int blocks = (int)((tot + 255) / 256);
    scores_kernel<<<blocks, 256, 0, stream>>>(cls, ws_scores, BN);
  }
  histthresh_kernel<<<BATCH, HT_THREADS, 0, stream>>>(ws_scores, Tb, ctr, N);
  dim3 cgrid((N + 1023) / 1024, BATCH);
  compact_kernel<<<cgrid, 1024, 0, stream>>>(ws_scores, Tb, ctr, csb, cidx, N);
  nmsout_kernel<<<BATCH, 256, 0, stream>>>(box, cls, csb, cidx, ctr,
                                           (float*)d_out, N);
}

// Round 15
// 150.072 us; speedup vs baseline: 1.1649x; 1.1649x over previous
//
#include <hip/hip_runtime.h>
#include <stdint.h>

#define BATCH 8
#define NCLS 80
#define MAXDET 100
#define CAP 512
#define NBINS 10240          // keys 0..9012 (score 1.0) fit without clamping
#define TT 1024              // tail kernel threads
#define TCHUNK 10            // 1024 threads * 10 bins = 10240
#define BASEKEY (0x3D4CCCCDu >> 12)   // float bits of 0.05f >> 12

// ---------------- Kernel 1: scores, 2 lanes per row, float4 loads, bit-exact ----
__global__ __launch_bounds__(256)
void scores_kernel(const float* __restrict__ cls,
                   float* __restrict__ scores, int BN) {
  int gid = blockIdx.x * 256 + threadIdx.x;
  int row = gid >> 1;
  int l = gid & 1;
  if (row >= BN) return;
  const float4* p4 = (const float4*)(cls + (size_t)row * NCLS);

  float4 v[10];
#pragma unroll
  for (int i = 0; i < 10; i++) v[i] = p4[l + 2 * i];

  float m = fmaxf(fmaxf(v[0].x, v[0].y), fmaxf(v[0].z, v[0].w));
#pragma unroll
  for (int i = 1; i < 10; i++)
    m = fmaxf(m, fmaxf(fmaxf(v[i].x, v[i].y), fmaxf(v[i].z, v[i].w)));
  m = fmaxf(m, __shfl_xor(m, 1));

  float a0 = 0.f, a1 = 0.f, a2 = 0.f, a3 = 0.f;
#pragma unroll
  for (int i = 0; i < 10; i++) {
    a0 += expf(v[i].x - m);
    a1 += expf(v[i].y - m);
    a2 += expf(v[i].z - m);
    a3 += expf(v[i].w - m);
  }
  float s_half = (a0 + a1) + (a2 + a3);      // (r8[4l]+r8[4l+1])+(r8[4l+2]+r8[4l+3])
  float s = s_half + __shfl_xor(s_half, 1);  // half0 + half1
  if (l == 0) scores[row] = 1.0f / s;
}

// ---------------- Kernel 2: fused tail — one block per batch ----------------
// Phase 1: LDS histogram + suffix scan -> threshold bin T (suffix count <= CAP).
// Phase 2: compact qualifying (score_bits, ~idx) keys directly into LDS sk[].
// Phase 3: bitonic sort desc. Phase 4: R10's chunked LDS-accb greedy walk
// (wave0 only). Phase 5: fused output (threads 0..99).
__global__ __launch_bounds__(TT)
void tail_kernel(const float* __restrict__ box, const float* __restrict__ cls,
                 const float* __restrict__ scores,
                 float* __restrict__ out, int N) {
  __shared__ uint32_t lh[NBINS];            // 40 KB
  __shared__ uint32_t chs[TT];              // 4 KB
  __shared__ unsigned long long sk[CAP];    // 4 KB
  __shared__ float sbox[CAP][4];            // 8 KB
  __shared__ uint32_t sidx[CAP];            // 2 KB
  __shared__ float4 accb[MAXDET];
  __shared__ uint32_t pick_i[MAXDET];
  __shared__ int T_sh, nacc_sh;
  __shared__ uint32_t lctr;

  const int b = blockIdx.x;
  const int tid = threadIdx.x;
  const float* sc = scores + (size_t)b * N;

  // ---- init ----
#pragma unroll
  for (int j = 0; j < TCHUNK; j++) lh[tid + j * TT] = 0;
  if (tid < CAP) sk[tid] = 0ULL;
  if (tid == 0) { lctr = 0; T_sh = NBINS; }
  __syncthreads();

  // ---- phase 1: histogram ----
  for (int i = tid; i < N; i += TT) {
    float s = sc[i];
    if (s >= 0.05f) {
      uint32_t key = (__float_as_uint(s) >> 12) - BASEKEY;
      atomicAdd(&lh[key], 1u);
    }
  }
  __syncthreads();

  // suffix scan over 1024 chunk sums
  uint32_t csum = 0;
#pragma unroll
  for (int j = 0; j < TCHUNK; j++) csum += lh[tid * TCHUNK + j];
  chs[tid] = csum;
  __syncthreads();
  for (int off = 1; off < TT; off <<= 1) {
    uint32_t v = chs[tid];
    uint32_t add = (tid + off < TT) ? chs[tid + off] : 0u;
    __syncthreads();
    chs[tid] = v + add;
    __syncthreads();
  }
  {
    uint32_t St = chs[tid];
    uint32_t Sprev = (tid > 0) ? chs[tid - 1] : 0xFFFFFFFFu;
    if (St <= CAP && (tid == 0 || Sprev > CAP)) {
      int T = 0;
      if (tid != 0) {
        uint32_t cum = St;
        int lo = (tid - 1) * TCHUNK;
        T = lo;
        for (int bb = tid * TCHUNK - 1; bb >= lo; bb--) {
          uint32_t nb = cum + lh[bb];
          if (nb > CAP) { T = bb + 1; break; }
          cum = nb;
          if (bb == lo) T = lo;
        }
      }
      T_sh = T;
    }
  }
  __syncthreads();
  const int T = T_sh;

  // ---- phase 2: compact keys into LDS (order irrelevant; sort fixes it) ----
  for (int i = tid; i < N; i += TT) {
    float s = sc[i];
    if (s >= 0.05f) {
      int key = (int)((__float_as_uint(s) >> 12) - BASEKEY);
      if (key >= T) {
        uint32_t slot = atomicAdd(&lctr, 1u);
        if (slot < CAP)
          sk[slot] = ((unsigned long long)__float_as_uint(s) << 32) |
                     (unsigned long long)(~(uint32_t)i);
      }
    }
  }
  __syncthreads();
  uint32_t nc = lctr; if (nc > CAP) nc = CAP;

  // ---- phase 3: bitonic sort, descending (512 active threads) ----
  for (int k = 2; k <= CAP; k <<= 1) {
    for (int j = k >> 1; j > 0; j >>= 1) {
      int i = tid;
      if (i < CAP) {
        int ixj = i ^ j;
        if (ixj > i) {
          unsigned long long a = sk[i], c = sk[ixj];
          if (((i & k) == 0) ? (a < c) : (a > c)) { sk[i] = c; sk[ixj] = a; }
        }
      }
      __syncthreads();
    }
  }

  // gather boxes of sorted candidates (corner-interp xywh form)
  if (tid < CAP) {
    unsigned long long k = sk[tid];
    uint32_t idx = (uint32_t)k ^ 0xFFFFFFFFu;
    sidx[tid] = idx;
    if (k != 0ULL) {
      const float4 f = *(const float4*)(box + ((size_t)b * N + idx) * 4);
      sbox[tid][0] = f.x; sbox[tid][1] = f.y;
      sbox[tid][2] = f.z - f.x; sbox[tid][3] = f.w - f.y;
    } else {
      sbox[tid][0] = 0.f; sbox[tid][1] = 0.f; sbox[tid][2] = 0.f; sbox[tid][3] = 0.f;
    }
  }
  __syncthreads();

  // ---- phase 4: R10's chunked accepted-list walk (wave0 only) ----
  if (tid < 64) {
    const int lane = tid;
    int nacc = 0;
    for (int cursor = 0; cursor < (int)nc && nacc < MAXDET; cursor += 64) {
      const int c = cursor + lane;
      bool alive = (c < (int)nc);
      float c0 = 0.f, c1 = 0.f, c2 = 0.f, c3 = 0.f;
      uint32_t myidx = 0;
      if (alive) {
        c0 = sbox[c][0]; c1 = sbox[c][1]; c2 = sbox[c][2]; c3 = sbox[c][3];
        myidx = sidx[c];
      }
      const float area_b = (c2 - c0) * (c3 - c1);

      // test chunk vs all accepted so far (float4 broadcast reads)
#pragma unroll 2
      for (int a = 0; a < nacc; a++) {
        float4 ar = accb[a];
        float area_r = (ar.z - ar.x) * (ar.w - ar.y);
        float ih = fmaxf(0.f, fminf(ar.z, c2) - fmaxf(ar.x, c0));
        float iw = fmaxf(0.f, fminf(ar.w, c3) - fmaxf(ar.y, c1));
        float inter = ih * iw;
        float uni = area_r + area_b - inter;
        bool okk = (area_r > 0.f) && (area_b > 0.f) && (uni > 0.f);
        float iou = okk ? (inter / uni) : 0.f;
        if (iou > 0.5f) alive = false;
      }

      unsigned long long am = __ballot(alive);
      while (am != 0ULL && nacc < MAXDET) {
        int L = (int)(__ffsll(am) - 1);
        float r0 = __shfl(c0, L), r1 = __shfl(c1, L);
        float r2 = __shfl(c2, L), r3 = __shfl(c3, L);
        uint32_t ridx = (uint32_t)__shfl((int)myidx, L);
        if (lane == 0) {
          pick_i[nacc] = ridx;
          accb[nacc] = make_float4(r0, r1, r2, r3);
        }
        asm volatile("s_waitcnt lgkmcnt(0)" ::: "memory");
        if (lane == L) alive = false;
        if (alive) {
          float area_r = (r2 - r0) * (r3 - r1);
          float ih = fmaxf(0.f, fminf(r2, c2) - fmaxf(r0, c0));
          float iw = fmaxf(0.f, fminf(r3, c3) - fmaxf(r1, c1));
          float inter = ih * iw;
          float uni = area_r + area_b - inter;
          bool okk = (area_r > 0.f) && (area_b > 0.f) && (uni > 0.f);
          float iou = okk ? (inter / uni) : 0.f;
          if (iou > 0.5f) alive = false;
        }
        am = __ballot(alive);
        nacc++;
      }
    }
    if (lane == 0) nacc_sh = nacc;
  }
  __syncthreads();

  // ---- phase 5: fused output, threads 0..MAXDET-1 ----
  const int nacc = nacc_sh;
  if (tid >= MAXDET) return;
  const int r = b * MAXDET + tid;
  float* boxes_out  = out;
  float* clsidx_out = out + BATCH * MAXDET * 4;
  float* cls_out    = out + BATCH * MAXDET * 4 + BATCH * MAXDET;

  if (tid >= nacc) {
    boxes_out[r * 4 + 0] = 0.f; boxes_out[r * 4 + 1] = 0.f;
    boxes_out[r * 4 + 2] = 0.f; boxes_out[r * 4 + 3] = 0.f;
    clsidx_out[r] = 0.f;
    for (int j = 0; j < NCLS; j++) cls_out[r * NCLS + j] = 0.f;
    return;
  }
  float4 bb = accb[tid];
  boxes_out[r * 4 + 0] = bb.x;
  boxes_out[r * 4 + 1] = bb.y;
  boxes_out[r * 4 + 2] = bb.z;
  boxes_out[r * 4 + 3] = bb.w;

  uint32_t idx = pick_i[tid];
  const float4* p = (const float4*)(cls + ((size_t)b * N + idx) * NCLS);
  float x[NCLS];
#pragma unroll
  for (int i = 0; i < NCLS / 4; i++) {
    float4 v = p[i];
    x[4 * i] = v.x; x[4 * i + 1] = v.y; x[4 * i + 2] = v.z; x[4 * i + 3] = v.w;
  }
  float m = x[0];
#pragma unroll
  for (int i = 1; i < NCLS; i++) m = fmaxf(m, x[i]);
  float r8[8];
#pragma unroll
  for (int j = 0; j < 8; j++) r8[j] = 0.0f;
#pragma unroll
  for (int i = 0; i < NCLS / 8; i++)
#pragma unroll
    for (int j = 0; j < 8; j++) r8[j] += expf(x[i * 8 + j] - m);
  float s = ((r8[0] + r8[1]) + (r8[2] + r8[3])) + ((r8[4] + r8[5]) + (r8[6] + r8[7]));

  float best = -1.f; int bi = 0;
  for (int j = 0; j < NCLS; j++) {
    float pj = expf(x[j] - m) / s;
    cls_out[r * NCLS + j] = pj;
    if (pj > best) { best = pj; bi = j; }
  }
  clsidx_out[r] = (float)bi;
}

extern "C" void kernel_launch(void* const* d_in, const int* in_sizes, int n_in,
                              void* d_out, int out_size, void* d_ws, size_t ws_size,
                              hipStream_t stream) {
  (void)n_in; (void)out_size; (void)ws_size;
  const float* box = (const float*)d_in[0];
  const float* cls = (const float*)d_in[1];
  const int N = in_sizes[0] / (BATCH * 4);
  const int BN = BATCH * N;

  float* ws_scores = (float*)d_ws;   // BN floats

  {
    long long tot = (long long)BN * 2;
    int blocks = (int)((tot + 255) / 256);
    scores_kernel<<<blocks, 256, 0, stream>>>(cls, ws_scores, BN);
  }
  tail_kernel<<<BATCH, TT, 0, stream>>>(box, cls, ws_scores, (float*)d_out, N);
}